// Round 9
// baseline (1588.923 us; speedup 1.0000x reference)
//
#include <hip/hip_runtime.h>

#define NTAGS  256
#define TLEN   512
#define BATCH  256
#define QS     68            // padded quarter stride (floats): lane-groups hit disjoint banks
#define NEGINF (-3.0e38f)

// One workgroup (1024 threads) per batch. Wave w owns columns 16w..16w+15;
// lane l: c = 16w + (l&15), quarter h = l>>4 scans prevs [64h, 64h+64).
// Per step: ALL 16 alpha float4s are loaded into a register array first
// (sched_barrier-pinned) so the DS queue pipelines them (~300 cyc total
// instead of 16 serialized ~120-cyc round trips), then the 320-op scan runs
// wait-free. Combine = shfl_xor butterfly, first-index tie-break. One barrier.
__global__ __launch_bounds__(1024, 4)
void viterbi_dp(const float* __restrict__ emis,   // [B][T][N]
                const float* __restrict__ mask,   // [B][T]
                const float* __restrict__ trans,  // [N][N]
                float* __restrict__ out)          // [B] scores ++ [B][T] paths (float)
{
    __shared__ __align__(16) float aSh[2][4 * QS];         // padded alpha, ping-pong
    __shared__ unsigned char bptL[(TLEN - 1) * NTAGS];     // 130816 B
    __shared__ float endS[NTAGS];

    const int tid   = threadIdx.x;
    const int w     = tid >> 6;
    const int lane  = tid & 63;
    const int c     = (w << 4) | (lane & 15);
    const int h     = lane >> 4;
    const int pbase = h << 6;
    const int b     = blockIdx.x;

    // 64 transition values trans[pbase+p][c], loaded once. AGPR-homing is
    // fine (direct VALU src); no pin — r6 showed pins force extra copies.
    float treg[64];
#pragma unroll
    for (int p = 0; p < 64; ++p)
        treg[p] = trans[(pbase + p) * NTAGS + c];

    const float* eb = emis + (size_t)b * TLEN * NTAGS;
    const float* mb = mask + (size_t)b * TLEN;

    // alphas0[c] = trans[SOS=0][c] + em[b][0][c]
    float aOld = trans[c] + eb[c];
    if (h == 0) aSh[0][QS * (c >> 6) + (c & 63)] = aOld;
    __syncthreads();

    float emCur = eb[NTAGS + c];
    float mCur  = mb[1];

    int cur = 0;
    for (int t = 1; t < TLEN; ++t) {
        float emNext = 0.0f, mNext = 1.0f;
        if (t + 1 < TLEN) {
            emNext = eb[(t + 1) * NTAGS + c];
            mNext  = mb[t + 1];
        }

        // ---- batch-issue all alpha loads into registers ----
        const float4* a4 = (const float4*)(&aSh[cur][h * QS]);
        float4 A[16];
#pragma unroll
        for (int q = 0; q < 16; ++q)
            A[q] = a4[q];
        __builtin_amdgcn_sched_barrier(0);   // keep the load cluster above the scan

        // scan my quarter: ascending p, strict > keeps FIRST max; rounding
        // exactly as reference: (alpha[p] + trans[p][c]) + em[c]
        float gb = NEGINF;
        int   ga = 0;
#pragma unroll
        for (int q = 0; q < 16; ++q) {
            float s;
            s = (A[q].x + treg[4 * q + 0]) + emCur; if (s > gb) { gb = s; ga = 4 * q + 0; }
            s = (A[q].y + treg[4 * q + 1]) + emCur; if (s > gb) { gb = s; ga = 4 * q + 1; }
            s = (A[q].z + treg[4 * q + 2]) + emCur; if (s > gb) { gb = s; ga = 4 * q + 2; }
            s = (A[q].w + treg[4 * q + 3]) + emCur; if (s > gb) { gb = s; ga = 4 * q + 3; }
        }
        ga += pbase;

        // butterfly combine across the 4 quarters (lanes xor 16, xor 32);
        // strictly larger, or equal with smaller index (= global first-max).
#pragma unroll
        for (int m = 16; m <= 32; m <<= 1) {
            const float pvv = __shfl_xor(gb, m, 64);
            const int   paa = __shfl_xor(ga, m, 64);
            const bool take = (pvv > gb) || ((pvv == gb) && (paa < ga));
            gb = take ? pvv : gb;
            ga = take ? paa : ga;
        }

        // masked blend exactly as reference: m*max + (1-m)*alpha
        const float aNew = mCur * gb + (1.0f - mCur) * aOld;
        if (h == 0)      aSh[cur ^ 1][QS * (c >> 6) + (c & 63)] = aNew;
        else if (h == 1) bptL[(t - 1) * NTAGS + c] = (unsigned char)ga;

        aOld  = aNew;
        emCur = emNext;
        mCur  = mNext;
        cur  ^= 1;
        __syncthreads();
    }

    // end_scores = alpha + trans[:, EOS=1]
    if (h == 0) endS[c] = aOld + trans[c * NTAGS + 1];
    __syncthreads();

    if (tid == 0) {
        float best = endS[0]; int arg = 0;
        for (int i = 1; i < NTAGS; ++i) {
            float v = endS[i];
            if (v > best) { best = v; arg = i; }
        }
        out[b] = best;

        // backtrace entirely from LDS
        float* pout = out + BATCH + (size_t)b * TLEN;
        int tag = arg;
        pout[TLEN - 1] = (float)tag;
        for (int t = TLEN - 2; t >= 0; --t) {
            tag = bptL[t * NTAGS + tag];
            pout[t] = (float)tag;
        }
    }
}

extern "C" void kernel_launch(void* const* d_in, const int* in_sizes, int n_in,
                              void* d_out, int out_size, void* d_ws, size_t ws_size,
                              hipStream_t stream) {
    (void)d_ws; (void)ws_size; (void)in_sizes; (void)n_in; (void)out_size;
    const float* emis  = (const float*)d_in[0];
    const float* mask  = (const float*)d_in[1];
    const float* trans = (const float*)d_in[2];
    float* out = (float*)d_out;

    viterbi_dp<<<dim3(BATCH), dim3(1024), 0, stream>>>(emis, mask, trans, out);
}

// Round 10
// 1529.548 us; speedup vs baseline: 1.0388x; 1.0388x over previous
//
#include <hip/hip_runtime.h>

#define NTAGS  256
#define TLEN   512
#define BATCH  256
#define BLK    36            // padded 32-float alpha block stride (8 blocks x 144B: disjoint banks)
#define NEGINF (-3.0e38f)

// One workgroup (1024 threads) per batch. Wave w owns columns [16w,16w+16).
// Lane l: group g = l>>3 scans prevs [32g, 32g+32) for TWO columns
// cA = 16w + (l&7), cB = cA + 8. trans in 64 regs/thread (AGPR-homed, free
// direct VALU src). Per step: 8 ds_read_b128 (half of r5), 4 independent
// compare chains (2 cols x 2-way split), 3-level shfl_xor butterfly with
// first-index tie-break. One barrier per step.
__global__ __launch_bounds__(1024, 4)
void viterbi_dp(const float* __restrict__ emis,   // [B][T][N]
                const float* __restrict__ mask,   // [B][T]
                const float* __restrict__ trans,  // [N][N]
                float* __restrict__ out)          // [B] scores ++ [B][T] paths (float)
{
    __shared__ __align__(16) float aSh[2][8 * BLK];        // padded alpha, ping-pong
    __shared__ unsigned char bptL[(TLEN - 1) * NTAGS];     // 130816 B
    __shared__ float endS[NTAGS];

    const int tid  = threadIdx.x;
    const int w    = tid >> 6;
    const int lane = tid & 63;
    const int g    = lane >> 3;
    const int j    = lane & 7;
    const int cA   = (w << 4) + j;
    const int cB   = cA + 8;
    const int pb   = g << 5;           // my 32 prevs: [pb, pb+32)
    const int b    = blockIdx.x;

    // 64 transition values (32 per column), loaded once; AGPR-homing is fine.
    float trA[32], trB[32];
#pragma unroll
    for (int p = 0; p < 32; ++p) {
        trA[p] = trans[(pb + p) * NTAGS + cA];
        trB[p] = trans[(pb + p) * NTAGS + cB];
    }

    const float* eb = emis + (size_t)b * TLEN * NTAGS;
    const float* mb = mask + (size_t)b * TLEN;

    // alphas0[c] = trans[SOS=0][c] + em[b][0][c]; padded addr: (c>>5)*BLK + (c&31)
    float aOldA = trans[cA] + eb[cA];
    float aOldB = trans[cB] + eb[cB];
    if (g == 0) {
        aSh[0][(cA >> 5) * BLK + (cA & 31)] = aOldA;
        aSh[0][(cB >> 5) * BLK + (cB & 31)] = aOldB;
    }
    __syncthreads();

    float emA = eb[NTAGS + cA], emB = eb[NTAGS + cB];
    float mCur = mb[1];

    int cur = 0;
    for (int t = 1; t < TLEN; ++t) {
        float emA2 = 0.0f, emB2 = 0.0f, mNext = 1.0f;
        if (t + 1 < TLEN) {
            emA2  = eb[(t + 1) * NTAGS + cA];
            emB2  = eb[(t + 1) * NTAGS + cB];
            mNext = mb[t + 1];
        }

        // my 32 alphas (broadcast within the 8-lane group; blocks on disjoint banks)
        const float4* aBlk = (const float4*)(&aSh[cur][g * BLK]);

        // scan: ascending p, strict > keeps FIRST max; rounding exactly as
        // reference: (alpha[p] + trans[p][c]) + em[c]. Two chains per column
        // (p<16 lo, p>=16 hi) for ILP; merged with index-order tie-break.
        float mAlo = NEGINF, mAhi = NEGINF, mBlo = NEGINF, mBhi = NEGINF;
        int   gAlo = 0,      gAhi = 16,     gBlo = 0,      gBhi = 16;
#pragma unroll
        for (int q = 0; q < 4; ++q) {
            const float4 lo = aBlk[q];
            const float4 hi = aBlk[q + 4];
            float s;
            s = (lo.x + trA[4*q+0])  + emA; if (s > mAlo) { mAlo = s; gAlo = 4*q+0; }
            s = (lo.y + trA[4*q+1])  + emA; if (s > mAlo) { mAlo = s; gAlo = 4*q+1; }
            s = (lo.z + trA[4*q+2])  + emA; if (s > mAlo) { mAlo = s; gAlo = 4*q+2; }
            s = (lo.w + trA[4*q+3])  + emA; if (s > mAlo) { mAlo = s; gAlo = 4*q+3; }
            s = (hi.x + trA[16+4*q+0]) + emA; if (s > mAhi) { mAhi = s; gAhi = 16+4*q+0; }
            s = (hi.y + trA[16+4*q+1]) + emA; if (s > mAhi) { mAhi = s; gAhi = 16+4*q+1; }
            s = (hi.z + trA[16+4*q+2]) + emA; if (s > mAhi) { mAhi = s; gAhi = 16+4*q+2; }
            s = (hi.w + trA[16+4*q+3]) + emA; if (s > mAhi) { mAhi = s; gAhi = 16+4*q+3; }
            s = (lo.x + trB[4*q+0])  + emB; if (s > mBlo) { mBlo = s; gBlo = 4*q+0; }
            s = (lo.y + trB[4*q+1])  + emB; if (s > mBlo) { mBlo = s; gBlo = 4*q+1; }
            s = (lo.z + trB[4*q+2])  + emB; if (s > mBlo) { mBlo = s; gBlo = 4*q+2; }
            s = (lo.w + trB[4*q+3])  + emB; if (s > mBlo) { mBlo = s; gBlo = 4*q+3; }
            s = (hi.x + trB[16+4*q+0]) + emB; if (s > mBhi) { mBhi = s; gBhi = 16+4*q+0; }
            s = (hi.y + trB[16+4*q+1]) + emB; if (s > mBhi) { mBhi = s; gBhi = 16+4*q+1; }
            s = (hi.z + trB[16+4*q+2]) + emB; if (s > mBhi) { mBhi = s; gBhi = 16+4*q+2; }
            s = (hi.w + trB[16+4*q+3]) + emB; if (s > mBhi) { mBhi = s; gBhi = 16+4*q+3; }
        }
        // merge hi into lo: hi indices all larger -> take hi only if strictly greater
        float vA = (mAhi > mAlo) ? mAhi : mAlo;
        int   iA = ((mAhi > mAlo) ? gAhi : gAlo) + pb;
        float vB = (mBhi > mBlo) ? mBhi : mBlo;
        int   iB = ((mBhi > mBlo) ? gBhi : gBlo) + pb;

        // butterfly across the 8 groups (lanes xor 8,16,32): strictly larger,
        // or equal with smaller index (= global first-max).
#pragma unroll
        for (int m = 8; m <= 32; m <<= 1) {
            const float pvA = __shfl_xor(vA, m, 64);
            const int   piA = __shfl_xor(iA, m, 64);
            const float pvB = __shfl_xor(vB, m, 64);
            const int   piB = __shfl_xor(iB, m, 64);
            bool tk = (pvA > vA) || ((pvA == vA) && (piA < iA));
            vA = tk ? pvA : vA;  iA = tk ? piA : iA;
            tk = (pvB > vB) || ((pvB == vB) && (piB < iB));
            vB = tk ? pvB : vB;  iB = tk ? piB : iB;
        }

        // masked blend exactly as reference: m*max + (1-m)*alpha
        const float aNewA = mCur * vA + (1.0f - mCur) * aOldA;
        const float aNewB = mCur * vB + (1.0f - mCur) * aOldB;
        if (g == 0) {
            aSh[cur ^ 1][(cA >> 5) * BLK + (cA & 31)] = aNewA;
            aSh[cur ^ 1][(cB >> 5) * BLK + (cB & 31)] = aNewB;
        } else if (g == 1) {
            bptL[(t - 1) * NTAGS + cA] = (unsigned char)iA;
            bptL[(t - 1) * NTAGS + cB] = (unsigned char)iB;
        }

        aOldA = aNewA;  aOldB = aNewB;
        emA = emA2;  emB = emB2;  mCur = mNext;
        cur ^= 1;
        __syncthreads();
    }

    // end_scores = alpha + trans[:, EOS=1]
    if (g == 0) {
        endS[cA] = aOldA + trans[cA * NTAGS + 1];
        endS[cB] = aOldB + trans[cB * NTAGS + 1];
    }
    __syncthreads();

    if (tid == 0) {
        float best = endS[0]; int arg = 0;
        for (int i = 1; i < NTAGS; ++i) {
            float v = endS[i];
            if (v > best) { best = v; arg = i; }
        }
        out[b] = best;

        // backtrace entirely from LDS
        float* pout = out + BATCH + (size_t)b * TLEN;
        int tag = arg;
        pout[TLEN - 1] = (float)tag;
        for (int t = TLEN - 2; t >= 0; --t) {
            tag = bptL[t * NTAGS + tag];
            pout[t] = (float)tag;
        }
    }
}

extern "C" void kernel_launch(void* const* d_in, const int* in_sizes, int n_in,
                              void* d_out, int out_size, void* d_ws, size_t ws_size,
                              hipStream_t stream) {
    (void)d_ws; (void)ws_size; (void)in_sizes; (void)n_in; (void)out_size;
    const float* emis  = (const float*)d_in[0];
    const float* mask  = (const float*)d_in[1];
    const float* trans = (const float*)d_in[2];
    float* out = (float*)d_out;

    viterbi_dp<<<dim3(BATCH), dim3(1024), 0, stream>>>(emis, mask, trans, out);
}